// Round 11
// baseline (519.012 us; speedup 1.0000x reference)
//
#include <hip/hip_runtime.h>
#include <math.h>

#define NN 30000
#define NE 400000
#define GMAX 55040            // groups upper bound: NN + NE/16, rounded up
#define TMAX 13760            // tile upper bound: GMAX/4

typedef _Float16 f16;
typedef _Float16 f16x8 __attribute__((ext_vector_type(8)));
typedef _Float16 f16x4 __attribute__((ext_vector_type(4)));
typedef float f32x4 __attribute__((ext_vector_type(4)));

// ---------- float atomic max via int/uint atomics (valid incl. -inf init) ----
__device__ __forceinline__ void atomic_max_f(float* addr, float v) {
    if (v >= 0.0f) {
        atomicMax((int*)addr, __float_as_int(v));
    } else {
        atomicMin((unsigned int*)addr, __float_as_uint(v));
    }
}

__global__ __launch_bounds__(256) void fill_neg_inf4(float4* p, int n4) {
    int i = blockIdx.x * blockDim.x + threadIdx.x;
    int stride = gridDim.x * blockDim.x;
    const float4 v = {-INFINITY, -INFINITY, -INFINITY, -INFINITY};
    for (; i < n4; i += stride) p[i] = v;
}

// ---------- CSR-16 build: histogram, group scan, meta, padded scatter --------
__global__ __launch_bounds__(256) void hist_dst(const int* __restrict__ dst,
                                                int* __restrict__ counts) {
    int e = blockIdx.x * 256 + threadIdx.x;
    if (e < NE) atomicAdd(&counts[dst[e]], 1);
}

// per node: groups = ceil(cnt/16); prefix -> goff; slot cursor = 16*goff; total
__global__ __launch_bounds__(1024) void scan_groups(const int* __restrict__ counts,
                                                    int* __restrict__ goff,
                                                    int* __restrict__ cursor,
                                                    int* __restrict__ gTot) {
    __shared__ int lsum[1024];
    const int t = threadIdx.x;
    const int base = t * 30;
    int s = 0;
    for (int i = 0; i < 30; ++i) {
        int idx = base + i;
        if (idx < NN) s += (counts[idx] + 15) >> 4;
    }
    lsum[t] = s;
    __syncthreads();
    int acc = s;
    for (int off = 1; off < 1024; off <<= 1) {
        int v = (t >= off) ? lsum[t - off] : 0;
        __syncthreads();
        acc += v;
        lsum[t] = acc;
        __syncthreads();
    }
    int run = acc - s;   // exclusive prefix
    for (int i = 0; i < 30; ++i) {
        int idx = base + i;
        if (idx < NN) {
            goff[idx] = run;
            cursor[idx] = run * 16;
            run += (counts[idx] + 15) >> 4;
        }
    }
    if (t == 1023) gTot[0] = acc;
}

__global__ __launch_bounds__(256) void build_meta(const int* __restrict__ counts,
                                                  const int* __restrict__ goff,
                                                  int* __restrict__ gnode,
                                                  int* __restrict__ gcnt,
                                                  int* __restrict__ gexcl) {
    int n = blockIdx.x * 256 + threadIdx.x;
    if (n >= NN) return;
    int c = counts[n];
    if (c == 0) return;
    int g0 = goff[n];
    int gpn = (c + 15) >> 4;
    for (int k = 0; k < gpn; ++k) {
        int rem = c - 16 * k;
        gnode[g0 + k] = n;
        gcnt[g0 + k] = rem > 16 ? 16 : rem;
        gexcl[g0 + k] = (gpn == 1) ? 1 : 0;
    }
}

__global__ __launch_bounds__(256) void scatter_pad(const int* __restrict__ src,
                                                   const int* __restrict__ dst,
                                                   int* __restrict__ cursor,
                                                   int* __restrict__ srcP) {
    int e = blockIdx.x * 256 + threadIdx.x;
    if (e >= NE) return;
    int d = dst[e];
    int p = atomicAdd(&cursor[d], 1);
    srcP[p] = src[e];
}

// ---------- pack weight (fp32 row-major KxN) into MFMA b-frag order, f16 -----
template<int K, int N>
__global__ __launch_bounds__(256) void pack_w(const float* __restrict__ wsrc,
                                              f16* __restrict__ pB) {
    int f = blockIdx.x * 256 + threadIdx.x;
    if (f >= K * N) return;
    int j = f & 7;
    int l = (f >> 3) & 63;
    int rest = f >> 9;
    constexpr int KS = K / 32;
    int ks = rest % KS;
    int nt = rest / KS;
    int k = ks * 32 + ((l >> 4) << 3) + j;
    int n = nt * 16 + (l & 15);
    pB[f] = (f16)wsrc[k * N + n];
}

// ---------- f32 -> f16 cast (for warel rows) ---------------------------------
__global__ __launch_bounds__(256) void cast_f16(const float* __restrict__ w,
                                                f16* __restrict__ o, int n) {
    int i = blockIdx.x * 256 + threadIdx.x;
    if (i < n) o[i] = (f16)w[i];
}

// ---------- layer-1 node linear (K=16, tiny): scalar -------------------------
template<int K, int COUT>
__global__ __launch_bounds__(256) void node_linear(const float* __restrict__ feat,
                                                   const float* __restrict__ wa,
                                                   const float* __restrict__ b,
                                                   f16* __restrict__ A) {
    constexpr int NPB = 8;
    constexpr int G   = 256 / COUT;
    constexpr int NPT = NPB / G;
    __shared__ float sf[NPB * K];
    const int node0 = blockIdx.x * NPB;
    for (int idx = threadIdx.x; idx < NPB * K; idx += 256) {
        float v = feat[node0 * K + idx];
        if (!isfinite(v)) v = 0.0f;
        sf[idx] = v;
    }
    __syncthreads();
    const int j  = threadIdx.x % COUT;
    const int g  = threadIdx.x / COUT;
    const int n0 = g * NPT;
    float acc[NPT];
#pragma unroll
    for (int i = 0; i < NPT; i++) acc[i] = 0.0f;
    for (int k = 0; k < K; k++) {
        float w = wa[k * COUT + j];
#pragma unroll
        for (int nn = 0; nn < NPT; nn++)
            acc[nn] = fmaf(sf[(n0 + nn) * K + k], w, acc[nn]);
    }
    const float bj = b[j];
#pragma unroll
    for (int nn = 0; nn < NPT; nn++)
        A[(size_t)(node0 + n0 + nn) * COUT + j] = (f16)(acc[nn] + bj);
}

// ---------- node GEMM via MFMA: A[n][C] = fixup(feat[n][K]) @ wa + bias -> f16
template<int K, int C>
__global__ __launch_bounds__(256) void node_gemm(const float* __restrict__ feat,
                                                 const f16* __restrict__ pW,
                                                 const float* __restrict__ bias,
                                                 f16* __restrict__ A) {
    constexpr int NTW = C / 64;
    constexpr int KS  = K / 32;
    __shared__ __align__(16) unsigned char smem[64 * K * 2];
    const int tid = threadIdx.x;
    const int node0 = blockIdx.x * 64;

    {
        const int e = tid >> 2, p = tid & 3;
        const bool valid = (node0 + e) < NN;
        const float* frow = feat + (size_t)(node0 + e) * K;
#pragma unroll
        for (int ch = 0; ch < K / 32; ++ch) {
            const int j0 = (ch * 4 + p) * 8;
            f16x8 hv;
#pragma unroll
            for (int jj = 0; jj < 8; ++jj) {
                float v = valid ? frow[j0 + jj] : 0.0f;
                if (!isfinite(v)) v = 0.0f;
                hv[jj] = (f16)v;
            }
            *(f16x8*)(smem + e * (K * 2) + ((j0 * 2) ^ ((e & 7) << 4))) = hv;
        }
    }
    __syncthreads();

    const int w = tid >> 6, l = tid & 63, lr = l & 15, lg = l >> 4;
    f32x4 acc[4][NTW] = {};
#pragma unroll
    for (int ks = 0; ks < KS; ++ks) {
        f16x8 af[4];
#pragma unroll
        for (int m = 0; m < 4; ++m) {
            const int row = m * 16 + lr;
            af[m] = *(const f16x8*)(smem + row * (K * 2)
                     + (((ks * 32 + lg * 8) * 2) ^ ((row & 7) << 4)));
        }
#pragma unroll
        for (int nt = 0; nt < NTW; ++nt) {
            const int ntg = w * NTW + nt;
            f16x8 bf = *(const f16x8*)(pW + ((size_t)(ntg * KS + ks) * 64 + l) * 8);
#pragma unroll
            for (int m = 0; m < 4; ++m)
                acc[m][nt] = __builtin_amdgcn_mfma_f32_16x16x32_f16(af[m], bf, acc[m][nt], 0, 0, 0);
        }
    }
#pragma unroll
    for (int m = 0; m < 4; ++m)
#pragma unroll
        for (int nt = 0; nt < NTW; ++nt) {
            const int col = w * (C / 4) + nt * 16 + lr;
            const float bv = bias[col];
#pragma unroll
            for (int rr = 0; rr < 4; ++rr) {
                const int row = m * 16 + lg * 4 + rr;
                if (node0 + row < NN)
                    A[(size_t)(node0 + row) * C + col] = (f16)(acc[m][nt][rr] + bv);
            }
        }
}

// ---------- edge kernel (CSR-16): tile = 4 groups x 16 rows, each group one
//            dst node (padded). h1=relu(Ah[srcP]+rel@warel) in LDS; MFMA;
//            epilogue = per-group masked max + 2 shfl + store/atomic ----------
template<int C, int NW>
__global__ __launch_bounds__(NW * 64, 4) void edge_mfma(const f16* __restrict__ Ah,
                                                        const f16* __restrict__ warelh, // 3 x C f16
                                                        const f16* __restrict__ pB,
                                                        const float* __restrict__ bb,
                                                        const float* __restrict__ pos,
                                                        const int* __restrict__ srcP,
                                                        const int* __restrict__ gnode,
                                                        const int* __restrict__ gcnt,
                                                        const int* __restrict__ gexcl,
                                                        const int* __restrict__ gTot,
                                                        float* __restrict__ agg) {
    constexpr int TE   = 64;
    constexpr int BLK  = NW * 64;
    constexpr int CW   = C / NW;        // cols per wave
    constexpr int NTW  = CW / 16;       // n-tiles per wave
    constexpr int KS   = C / 32;        // k-steps
    constexpr int CPR  = C / 8;         // f16x8 chunks per row
    constexpr int LOGCPR = (C == 256) ? 5 : (C == 128 ? 4 : 3);
    constexpr int CH   = (TE * CPR) / BLK;  // chunks per thread
    static_assert(NTW >= 1 && CH >= 2, "geometry");

    __shared__ __align__(16) unsigned char h1[TE * C * 2];  // f16, XOR-swizzled
    __shared__ __align__(16) f16 s_warel[3 * C];
    __shared__ __align__(8)  f16 s_rel[TE][4];
    __shared__ int s_gn[4], s_gc[4], s_ge[4];

    const int tid = threadIdx.x;
    const int nwg = gridDim.x;
    const int q8 = nwg >> 3, r8 = nwg & 7;
    const int xcd = blockIdx.x & 7, o = blockIdx.x >> 3;
    const int bid = (xcd < r8 ? xcd * (q8 + 1) : r8 * (q8 + 1) + (xcd - r8) * q8) + o;

    const int g0 = bid * 4;
    if (g0 >= gTot[0]) return;          // wave-uniform early exit (no barrier yet)
    const int r0 = bid * TE;            // padded slot base

    // ---- early-issue A-gather (pad slots read Ah[0]: cached, harmless)
    const int slot = tid & (CPR - 1);
    int sv[CH];
    f16x8 av[CH];
#pragma unroll
    for (int i = 0; i < CH; ++i)
        sv[i] = srcP[r0 + ((i * BLK + tid) >> LOGCPR)];
    av[0] = *(const f16x8*)(Ah + (size_t)sv[0] * C + slot * 8);
    av[1] = *(const f16x8*)(Ah + (size_t)sv[1] * C + slot * 8);

    // ---- meta: group info + per-row rel
    if (tid < 4) {
        s_gn[tid] = gnode[g0 + tid];
        s_gc[tid] = gcnt[g0 + tid];
        s_ge[tid] = gexcl[g0 + tid];
    }
    if (tid < TE) {
        int s = srcP[r0 + tid];
        int d = gnode[g0 + (tid >> 4)];
        s_rel[tid][0] = (f16)(pos[3 * s + 0] - pos[3 * d + 0]);
        s_rel[tid][1] = (f16)(pos[3 * s + 1] - pos[3 * d + 1]);
        s_rel[tid][2] = (f16)(pos[3 * s + 2] - pos[3 * d + 2]);
        s_rel[tid][3] = (f16)0.f;
    }
    for (int i = tid; i < 3 * C / 8; i += BLK)
        ((f16x8*)s_warel)[i] = ((const f16x8*)warelh)[i];
    __syncthreads();

    // ---- phase 1: h1 = relu(A[src] + rel@warel) into LDS (packed f16)
    {
        const f16* wp = s_warel + slot * 8;
        const f16x8 w0 = *(const f16x8*)(wp);
        const f16x8 w1 = *(const f16x8*)(wp + C);
        const f16x8 w2 = *(const f16x8*)(wp + 2 * C);
#pragma unroll
        for (int i = 0; i < CH; ++i) {
            if (i + 2 < CH)
                av[i + 2] = *(const f16x8*)(Ah + (size_t)sv[i + 2] * C + slot * 8);
            const int row = (i * BLK + tid) >> LOGCPR;
            const f16x4 rl = *(const f16x4*)&s_rel[row][0];
            const f16 rx = rl[0], ry = rl[1], rz = rl[2];
            const f16x8 rxv = {rx, rx, rx, rx, rx, rx, rx, rx};
            const f16x8 ryv = {ry, ry, ry, ry, ry, ry, ry, ry};
            const f16x8 rzv = {rz, rz, rz, rz, rz, rz, rz, rz};
            f16x8 hv = av[i] + rxv * w0 + ryv * w1 + rzv * w2;
#pragma unroll
            for (int jj = 0; jj < 8; ++jj)
                hv[jj] = hv[jj] > (f16)0.f ? hv[jj] : (f16)0.f;
            *(f16x8*)(h1 + row * (2 * C) + ((slot * 16) ^ ((row & 7) << 4))) = hv;
        }
    }
    __syncthreads();

    // ---- phase 2: msg = h1 @ wb via MFMA (wave: 64 rows x CW cols)
    const int w = tid >> 6, l = tid & 63, lr = l & 15, lg = l >> 4;
    f32x4 acc[4][NTW] = {};
    __builtin_amdgcn_s_setprio(1);
#pragma unroll
    for (int ks = 0; ks < KS; ++ks) {
        f16x8 af[4];
#pragma unroll
        for (int m = 0; m < 4; ++m) {
            const int row = m * 16 + lr;
            af[m] = *(const f16x8*)(h1 + row * (2 * C)
                     + (((ks * 32 + lg * 8) * 2) ^ ((row & 7) << 4)));
        }
#pragma unroll
        for (int nt = 0; nt < NTW; ++nt) {
            f16x8 bf = *(const f16x8*)(pB + ((size_t)((w * NTW + nt) * KS + ks) * 64 + l) * 8);
#pragma unroll
            for (int m = 0; m < 4; ++m)
                acc[m][nt] = __builtin_amdgcn_mfma_f32_16x16x32_f16(af[m], bf, acc[m][nt], 0, 0, 0);
        }
    }
    __builtin_amdgcn_s_setprio(0);

    // ---- phase 3: per-group masked max (pad rows excluded) + flush
    float bbv[NTW];
#pragma unroll
    for (int nt = 0; nt < NTW; ++nt) bbv[nt] = bb[w * CW + nt * 16 + lr];

#pragma unroll
    for (int m = 0; m < 4; ++m) {
        const int cnt = s_gc[m];
        if (cnt == 0) continue;                 // wave-uniform (tail groups)
        const int node = s_gn[m];
        const bool excl = s_ge[m] != 0;
        bool ok[4];
#pragma unroll
        for (int rr = 0; rr < 4; ++rr) ok[rr] = (lg * 4 + rr) < cnt;
#pragma unroll
        for (int nt = 0; nt < NTW; ++nt) {
            float v = -INFINITY;
#pragma unroll
            for (int rr = 0; rr < 4; ++rr)
                v = fmaxf(v, ok[rr] ? acc[m][nt][rr] : -INFINITY);
            v = fmaxf(v, __shfl_xor(v, 16, 64));
            v = fmaxf(v, __shfl_xor(v, 32, 64));
            if (lg == 0) {
                float* addr = &agg[(size_t)node * C + w * CW + nt * 16 + lr];
                const float outv = v + bbv[nt];
                if (excl) *addr = outv;          // single-group node: sole writer
                else      atomic_max_f(addr, outv);
            }
        }
    }
}

// ---------- projection step 1: coalesced atomic scatter into pixel-major img -
__global__ __launch_bounds__(256) void scatter_img(const float* __restrict__ feat, // N x 256
                                                   const float* __restrict__ pos,
                                                   const float* __restrict__ Km,
                                                   const int* __restrict__ batch,
                                                   float* __restrict__ img) {  // [B*4800][256]
    const int n0 = blockIdx.x * 8;
    const int c = threadIdx.x;
    const float k00 = Km[0], k02 = Km[2], k11 = Km[4], k12 = Km[5];
#pragma unroll
    for (int k = 0; k < 8; ++k) {
        const int n = n0 + k;
        const float X = pos[3 * n + 0], Y = pos[3 * n + 1], Z = pos[3 * n + 2];
        const int u = (int)((k00 * X / Z + k02) / 640.0f * 80.0f);
        const int v = (int)((k11 * Y / Z + k12) / 480.0f * 60.0f);
        if (u < 0 || u >= 80 || v < 0 || v >= 60) continue;
        const int p = (batch[n] * 60 + v) * 80 + u;
        float val = feat[(size_t)n * 256 + c];
        if (!isfinite(val)) val = 0.0f;
        atomicAdd(img + (size_t)p * 256 + c, val);
    }
}

// ---------- projection step 2: tiled transpose img[b][p][c] -> out[b][c][p] --
__global__ __launch_bounds__(256) void transpose_img(const float* __restrict__ img,
                                                     float* __restrict__ out) {
    __shared__ float tile[32][33];
    const int b = blockIdx.z;
    const int p0 = blockIdx.x * 32, c0 = blockIdx.y * 32;
    const float* src = img + (size_t)b * 4800 * 256;
    float* dst = out + (size_t)b * 256 * 4800;
    const int tx = threadIdx.x & 31, ty = threadIdx.x >> 5;
#pragma unroll
    for (int i = 0; i < 32; i += 8)
        tile[ty + i][tx] = src[(size_t)(p0 + ty + i) * 256 + c0 + tx];
    __syncthreads();
#pragma unroll
    for (int i = 0; i < 32; i += 8)
        dst[(size_t)(c0 + ty + i) * 4800 + p0 + tx] = tile[tx][ty + i];
}

// ---------------------------------------------------------------------------
extern "C" void kernel_launch(void* const* d_in, const int* in_sizes, int n_in,
                              void* d_out, int out_size, void* d_ws, size_t ws_size,
                              hipStream_t stream) {
    const float* x   = (const float*)d_in[0];
    const float* pos = (const float*)d_in[1];
    const float* Km  = (const float*)d_in[2];
    const float* w11 = (const float*)d_in[3];
    const float* b11 = (const float*)d_in[4];
    const float* w12 = (const float*)d_in[5];
    const float* b12 = (const float*)d_in[6];
    const float* w21 = (const float*)d_in[7];
    const float* b21 = (const float*)d_in[8];
    const float* w22 = (const float*)d_in[9];
    const float* b22 = (const float*)d_in[10];
    const float* w31 = (const float*)d_in[11];
    const float* b31 = (const float*)d_in[12];
    const float* w32 = (const float*)d_in[13];
    const float* b32 = (const float*)d_in[14];
    const int* edge  = (const int*)d_in[15];
    const int* batch = (const int*)d_in[16];
    const int* srcp = edge;
    const int* dstp = edge + NE;
    float* out = (float*)d_out;

    // workspace layout
    float* aggA  = (float*)d_ws;                      // N x 256 f32 (also img buffer)
    float* aggB  = aggA + (size_t)NN * 256;           // N x 256 f32
    f16*   Ah    = (f16*)(aggB + (size_t)NN * 256);   // N x 256 f16
    int*   srcP  = (int*)(Ah + (size_t)NN * 256);     // TMAX*64 padded slots
    int*   counts = srcP + (size_t)TMAX * 64;         // N
    int*   goff   = counts + NN;                      // N
    int*   cursor = goff + NN;                        // N
    int*   gTot   = cursor + NN;                      // 1 (+pad)
    int*   gnode  = gTot + 16;                        // GMAX
    int*   gcnt   = gnode + GMAX;                     // GMAX
    int*   gexcl  = gcnt + GMAX;                      // GMAX
    f16*   pW1   = (f16*)(gexcl + GMAX);              // 64*64
    f16*   pW2   = pW1 + 64 * 64;                     // 128*128
    f16*   pW3   = pW2 + 128 * 128;                   // 256*256
    f16*   pW2n  = pW3 + 256 * 256;                   // 64*128  (node L2)
    f16*   pW3n  = pW2n + 64 * 128;                   // 128*256 (node L3)
    f16*   wr1   = pW3n + 128 * 256;                  // 3*64 f16
    f16*   wr2   = wr1 + 3 * 64;                      // 3*128
    f16*   wr3   = wr2 + 3 * 128;                     // 3*256

    // ---- CSR-16 build (reused by all 3 layers)
    hipMemsetAsync(counts, 0, NN * sizeof(int), stream);
    hipMemsetAsync(srcP, 0, (size_t)TMAX * 64 * sizeof(int), stream);
    hipMemsetAsync(gnode, 0, GMAX * sizeof(int), stream);
    hipMemsetAsync(gcnt, 0, GMAX * sizeof(int), stream);
    hist_dst<<<(NE + 255) / 256, 256, 0, stream>>>(dstp, counts);
    scan_groups<<<1, 1024, 0, stream>>>(counts, goff, cursor, gTot);
    build_meta<<<(NN + 255) / 256, 256, 0, stream>>>(counts, goff, gnode, gcnt, gexcl);
    scatter_pad<<<(NE + 255) / 256, 256, 0, stream>>>(srcp, dstp, cursor, srcP);

    // ---- pack weights
    pack_w<64, 64><<<(64 * 64 + 255) / 256, 256, 0, stream>>>(w12, pW1);
    pack_w<128, 128><<<(128 * 128 + 255) / 256, 256, 0, stream>>>(w22, pW2);
    pack_w<256, 256><<<(256 * 256 + 255) / 256, 256, 0, stream>>>(w32, pW3);
    pack_w<64, 128><<<(64 * 128 + 255) / 256, 256, 0, stream>>>(w21, pW2n);
    pack_w<128, 256><<<(128 * 256 + 255) / 256, 256, 0, stream>>>(w31, pW3n);
    cast_f16<<<1, 256, 0, stream>>>(w11 + 16 * 64, wr1, 3 * 64);
    cast_f16<<<2, 256, 0, stream>>>(w21 + 64 * 128, wr2, 3 * 128);
    cast_f16<<<3, 256, 0, stream>>>(w31 + 128 * 256, wr3, 3 * 256);

    // ---- layer 1: cin=16, cout=64
    node_linear<16, 64><<<NN / 8, 256, 0, stream>>>(x, w11, b11, Ah);
    fill_neg_inf4<<<512, 256, 0, stream>>>((float4*)aggB, NN * 64 / 4);
    edge_mfma<64, 4><<<TMAX, 256, 0, stream>>>(Ah, wr1, pW1, b12, pos,
                                               srcP, gnode, gcnt, gexcl, gTot, aggB);
    // ---- layer 2: cin=64, cout=128
    node_gemm<64, 128><<<(NN + 63) / 64, 256, 0, stream>>>(aggB, pW2n, b21, Ah);
    fill_neg_inf4<<<512, 256, 0, stream>>>((float4*)aggA, NN * 128 / 4);
    edge_mfma<128, 8><<<TMAX, 512, 0, stream>>>(Ah, wr2, pW2, b22, pos,
                                                srcP, gnode, gcnt, gexcl, gTot, aggA);
    // ---- layer 3: cin=128, cout=256
    node_gemm<128, 256><<<(NN + 63) / 64, 256, 0, stream>>>(aggA, pW3n, b31, Ah);
    fill_neg_inf4<<<512, 256, 0, stream>>>((float4*)aggB, NN * 256 / 4);
    edge_mfma<256, 8><<<TMAX, 512, 0, stream>>>(Ah, wr3, pW3, b32, pos,
                                                srcP, gnode, gcnt, gexcl, gTot, aggB);
    // ---- projection: coalesced scatter into pixel-major img, then transpose
    hipMemsetAsync(aggA, 0, (size_t)4 * 4800 * 256 * sizeof(float), stream);
    scatter_img<<<NN / 8, 256, 0, stream>>>(aggB, pos, Km, batch, aggA);
    transpose_img<<<dim3(150, 8, 4), 256, 0, stream>>>(aggA, out);
}

// Round 12
// 368.241 us; speedup vs baseline: 1.4094x; 1.4094x over previous
//
#include <hip/hip_runtime.h>
#include <math.h>

#define NN 30000
#define NE 400000

typedef _Float16 f16;
typedef _Float16 f16x8 __attribute__((ext_vector_type(8)));
typedef _Float16 f16x4 __attribute__((ext_vector_type(4)));
typedef float f32x4 __attribute__((ext_vector_type(4)));

// ---------- float atomic max via int/uint atomics (valid incl. -inf init) ----
__device__ __forceinline__ void atomic_max_f(float* addr, float v) {
    if (v >= 0.0f) {
        atomicMax((int*)addr, __float_as_int(v));
    } else {
        atomicMin((unsigned int*)addr, __float_as_uint(v));
    }
}

__global__ __launch_bounds__(256) void fill_neg_inf4(float4* p, int n4) {
    int i = blockIdx.x * blockDim.x + threadIdx.x;
    int stride = gridDim.x * blockDim.x;
    const float4 v = {-INFINITY, -INFINITY, -INFINITY, -INFINITY};
    for (; i < n4; i += stride) p[i] = v;
}

// ---------- counting-sort of edges by dst --------------------------------
__global__ __launch_bounds__(256) void hist_dst(const int* __restrict__ dst,
                                                int* __restrict__ counts) {
    int e = blockIdx.x * 256 + threadIdx.x;
    if (e < NE) atomicAdd(&counts[dst[e]], 1);
}

__global__ __launch_bounds__(1024) void scan_counts(const int* __restrict__ counts,
                                                    int* __restrict__ cursor) {
    __shared__ int lsum[1024];
    const int t = threadIdx.x;
    const int base = t * 30;
    int s = 0;
    for (int i = 0; i < 30; ++i) {
        int idx = base + i;
        if (idx < NN) s += counts[idx];
    }
    lsum[t] = s;
    __syncthreads();
    int acc = s;
    for (int off = 1; off < 1024; off <<= 1) {
        int v = (t >= off) ? lsum[t - off] : 0;
        __syncthreads();
        acc += v;
        lsum[t] = acc;
        __syncthreads();
    }
    int run = acc - s;
    for (int i = 0; i < 30; ++i) {
        int idx = base + i;
        if (idx < NN) { cursor[idx] = run; run += counts[idx]; }
    }
}

__global__ __launch_bounds__(256) void scatter_edges(const int* __restrict__ src,
                                                     const int* __restrict__ dst,
                                                     int* __restrict__ cursor,
                                                     int* __restrict__ srcS,
                                                     int* __restrict__ dstS) {
    int e = blockIdx.x * 256 + threadIdx.x;
    if (e >= NE) return;
    int d = dst[e];
    int p = atomicAdd(&cursor[d], 1);
    srcS[p] = src[e];
    dstS[p] = d;
}

// ---------- fused prep: 5 weight packs + 3 warel casts in ONE launch ---------
// pack layout: flat = ((nt*(K/32)+ks)*64 + lane)*8 + j ;
//   k = ks*32 + (lane>>4)*8 + j ; n = nt*16 + (lane&15)
__device__ __forceinline__ void pack_one(const float* __restrict__ wsrc,
                                         f16* __restrict__ pB, int f, int K, int N) {
    int j = f & 7;
    int l = (f >> 3) & 63;
    int rest = f >> 9;
    int KS = K >> 5;
    int ks = rest % KS;
    int nt = rest / KS;
    int k = ks * 32 + ((l >> 4) << 3) + j;
    int n = nt * 16 + (l & 15);
    pB[f] = (f16)wsrc[k * N + n];
}

__global__ __launch_bounds__(256) void prep_all(const float* __restrict__ w12, f16* pW1,
                                                const float* __restrict__ w22, f16* pW2,
                                                const float* __restrict__ w32, f16* pW3,
                                                const float* __restrict__ w21, f16* pW2n,
                                                const float* __restrict__ w31, f16* pW3n,
                                                const float* __restrict__ wr1s, f16* wr1,
                                                const float* __restrict__ wr2s, f16* wr2,
                                                const float* __restrict__ wr3s, f16* wr3) {
    int i = blockIdx.x * 256 + threadIdx.x;
    // ranges: 4096 | 16384 | 65536 | 8192 | 32768 | 192 | 384 | 768
    if (i < 4096) { pack_one(w12, pW1, i, 64, 64); return; }
    i -= 4096;
    if (i < 16384) { pack_one(w22, pW2, i, 128, 128); return; }
    i -= 16384;
    if (i < 65536) { pack_one(w32, pW3, i, 256, 256); return; }
    i -= 65536;
    if (i < 8192) { pack_one(w21, pW2n, i, 64, 128); return; }
    i -= 8192;
    if (i < 32768) { pack_one(w31, pW3n, i, 128, 256); return; }
    i -= 32768;
    if (i < 192) { wr1[i] = (f16)wr1s[i]; return; }
    i -= 192;
    if (i < 384) { wr2[i] = (f16)wr2s[i]; return; }
    i -= 384;
    if (i < 768) { wr3[i] = (f16)wr3s[i]; return; }
}

// ---------- layer-1 node linear (K=16, tiny): scalar -------------------------
template<int K, int COUT>
__global__ __launch_bounds__(256) void node_linear(const float* __restrict__ feat,
                                                   const float* __restrict__ wa,
                                                   const float* __restrict__ b,
                                                   f16* __restrict__ A) {
    constexpr int NPB = 8;
    constexpr int G   = 256 / COUT;
    constexpr int NPT = NPB / G;
    __shared__ float sf[NPB * K];
    const int node0 = blockIdx.x * NPB;
    for (int idx = threadIdx.x; idx < NPB * K; idx += 256) {
        float v = feat[node0 * K + idx];
        if (!isfinite(v)) v = 0.0f;
        sf[idx] = v;
    }
    __syncthreads();
    const int j  = threadIdx.x % COUT;
    const int g  = threadIdx.x / COUT;
    const int n0 = g * NPT;
    float acc[NPT];
#pragma unroll
    for (int i = 0; i < NPT; i++) acc[i] = 0.0f;
    for (int k = 0; k < K; k++) {
        float w = wa[k * COUT + j];
#pragma unroll
        for (int nn = 0; nn < NPT; nn++)
            acc[nn] = fmaf(sf[(n0 + nn) * K + k], w, acc[nn]);
    }
    const float bj = b[j];
#pragma unroll
    for (int nn = 0; nn < NPT; nn++)
        A[(size_t)(node0 + n0 + nn) * COUT + j] = (f16)(acc[nn] + bj);
}

// ---------- node GEMM via MFMA: A[n][C] = fixup(feat[n][K]) @ wa + bias -> f16
template<int K, int C>
__global__ __launch_bounds__(256) void node_gemm(const float* __restrict__ feat,
                                                 const f16* __restrict__ pW,
                                                 const float* __restrict__ bias,
                                                 f16* __restrict__ A) {
    constexpr int NTW = C / 64;
    constexpr int KS  = K / 32;
    __shared__ __align__(16) unsigned char smem[64 * K * 2];
    const int tid = threadIdx.x;
    const int node0 = blockIdx.x * 64;

    {
        const int e = tid >> 2, p = tid & 3;
        const bool valid = (node0 + e) < NN;
        const float* frow = feat + (size_t)(node0 + e) * K;
#pragma unroll
        for (int ch = 0; ch < K / 32; ++ch) {
            const int j0 = (ch * 4 + p) * 8;
            f16x8 hv;
#pragma unroll
            for (int jj = 0; jj < 8; ++jj) {
                float v = valid ? frow[j0 + jj] : 0.0f;
                if (!isfinite(v)) v = 0.0f;
                hv[jj] = (f16)v;
            }
            *(f16x8*)(smem + e * (K * 2) + ((j0 * 2) ^ ((e & 7) << 4))) = hv;
        }
    }
    __syncthreads();

    const int w = tid >> 6, l = tid & 63, lr = l & 15, lg = l >> 4;
    f32x4 acc[4][NTW] = {};
#pragma unroll
    for (int ks = 0; ks < KS; ++ks) {
        f16x8 af[4];
#pragma unroll
        for (int m = 0; m < 4; ++m) {
            const int row = m * 16 + lr;
            af[m] = *(const f16x8*)(smem + row * (K * 2)
                     + (((ks * 32 + lg * 8) * 2) ^ ((row & 7) << 4)));
        }
#pragma unroll
        for (int nt = 0; nt < NTW; ++nt) {
            const int ntg = w * NTW + nt;
            f16x8 bf = *(const f16x8*)(pW + ((size_t)(ntg * KS + ks) * 64 + l) * 8);
#pragma unroll
            for (int m = 0; m < 4; ++m)
                acc[m][nt] = __builtin_amdgcn_mfma_f32_16x16x32_f16(af[m], bf, acc[m][nt], 0, 0, 0);
        }
    }
#pragma unroll
    for (int m = 0; m < 4; ++m)
#pragma unroll
        for (int nt = 0; nt < NTW; ++nt) {
            const int col = w * (C / 4) + nt * 16 + lr;
            const float bv = bias[col];
#pragma unroll
            for (int rr = 0; rr < 4; ++rr) {
                const int row = m * 16 + lg * 4 + rr;
                if (node0 + row < NN)
                    A[(size_t)(node0 + row) * C + col] = (f16)(acc[m][nt][rr] + bv);
            }
        }
}

// ---------- edge kernel (TE=64): early-issue A-gather; h1 in LDS; MFMA;
//            ballot segmented max; interior runs -> plain store ---------------
template<int C, int NW>
__global__ __launch_bounds__(NW * 64, 4) void edge_mfma(const f16* __restrict__ Ah,
                                                        const f16* __restrict__ warelh, // 3 x C f16
                                                        const f16* __restrict__ pB,
                                                        const float* __restrict__ bb,
                                                        const float* __restrict__ pos,
                                                        const int* __restrict__ srcS,
                                                        const int* __restrict__ dstS,
                                                        float* __restrict__ agg) {
    constexpr int TE   = 64;
    constexpr int BLK  = NW * 64;
    constexpr int CW   = C / NW;        // cols per wave
    constexpr int NTW  = CW / 16;       // n-tiles per wave
    constexpr int KS   = C / 32;        // k-steps
    constexpr int CPR  = C / 8;         // f16x8 chunks per row
    constexpr int LOGCPR = (C == 256) ? 5 : (C == 128 ? 4 : 3);
    constexpr int CH   = (TE * CPR) / BLK;  // chunks per thread
    static_assert(NTW >= 1 && CH >= 2, "geometry");

    __shared__ __align__(16) unsigned char h1[TE * C * 2];  // f16, XOR-swizzled
    __shared__ __align__(16) f16 s_warel[3 * C];
    __shared__ __align__(8)  f16 s_rel[TE][4];
    __shared__ int s_dst[TE];

    const int tid = threadIdx.x;
    const int nwg = gridDim.x;
    const int q8 = nwg >> 3, r8 = nwg & 7;
    const int xcd = blockIdx.x & 7, o = blockIdx.x >> 3;
    const int bid = (xcd < r8 ? xcd * (q8 + 1) : r8 * (q8 + 1) + (xcd - r8) * q8) + o;
    const int e0 = bid * TE;

    // ---- early-issue A-gather (no dependence on the meta barrier)
    const int slot = tid & (CPR - 1);
    int sv[CH];
    f16x8 av[CH];
#pragma unroll
    for (int i = 0; i < CH; ++i)
        sv[i] = srcS[e0 + ((i * BLK + tid) >> LOGCPR)];
    av[0] = *(const f16x8*)(Ah + (size_t)sv[0] * C + slot * 8);
    av[1] = *(const f16x8*)(Ah + (size_t)sv[1] * C + slot * 8);

    // ---- meta: rel (f16) + dst into LDS
    if (tid < TE) {
        int s = srcS[e0 + tid], d = dstS[e0 + tid];
        s_dst[tid] = d;
        s_rel[tid][0] = (f16)(pos[3 * s + 0] - pos[3 * d + 0]);
        s_rel[tid][1] = (f16)(pos[3 * s + 1] - pos[3 * d + 1]);
        s_rel[tid][2] = (f16)(pos[3 * s + 2] - pos[3 * d + 2]);
        s_rel[tid][3] = (f16)0.f;
    }
    for (int i = tid; i < 3 * C / 8; i += BLK)
        ((f16x8*)s_warel)[i] = ((const f16x8*)warelh)[i];
    __syncthreads();

    // ---- phase 1: h1 = relu(A[src] + rel@warel) into LDS (packed f16)
    {
        const f16* wp = s_warel + slot * 8;
        const f16x8 w0 = *(const f16x8*)(wp);
        const f16x8 w1 = *(const f16x8*)(wp + C);
        const f16x8 w2 = *(const f16x8*)(wp + 2 * C);
#pragma unroll
        for (int i = 0; i < CH; ++i) {
            if (i + 2 < CH)  // keep 2 gathers in flight
                av[i + 2] = *(const f16x8*)(Ah + (size_t)sv[i + 2] * C + slot * 8);
            const int row = (i * BLK + tid) >> LOGCPR;
            const f16x4 rl = *(const f16x4*)&s_rel[row][0];
            const f16 rx = rl[0], ry = rl[1], rz = rl[2];
            const f16x8 rxv = {rx, rx, rx, rx, rx, rx, rx, rx};
            const f16x8 ryv = {ry, ry, ry, ry, ry, ry, ry, ry};
            const f16x8 rzv = {rz, rz, rz, rz, rz, rz, rz, rz};
            f16x8 hv = av[i] + rxv * w0 + ryv * w1 + rzv * w2;
#pragma unroll
            for (int jj = 0; jj < 8; ++jj)
                hv[jj] = hv[jj] > (f16)0.f ? hv[jj] : (f16)0.f;
            *(f16x8*)(h1 + row * (2 * C) + ((slot * 16) ^ ((row & 7) << 4))) = hv;
        }
    }
    __syncthreads();

    // ---- phase 2: msg = h1 @ wb via MFMA (wave: 64 rows x CW cols)
    const int w = tid >> 6, l = tid & 63, lr = l & 15, lg = l >> 4;
    f32x4 acc[4][NTW] = {};
    __builtin_amdgcn_s_setprio(1);
#pragma unroll
    for (int ks = 0; ks < KS; ++ks) {
        f16x8 af[4];
#pragma unroll
        for (int m = 0; m < 4; ++m) {
            const int row = m * 16 + lr;
            af[m] = *(const f16x8*)(h1 + row * (2 * C)
                     + (((ks * 32 + lg * 8) * 2) ^ ((row & 7) << 4)));
        }
#pragma unroll
        for (int nt = 0; nt < NTW; ++nt) {
            f16x8 bf = *(const f16x8*)(pB + ((size_t)((w * NTW + nt) * KS + ks) * 64 + l) * 8);
#pragma unroll
            for (int m = 0; m < 4; ++m)
                acc[m][nt] = __builtin_amdgcn_mfma_f32_16x16x32_f16(af[m], bf, acc[m][nt], 0, 0, 0);
        }
    }
    __builtin_amdgcn_s_setprio(0);

    // ---- phase 3: register segmented max; interior run -> plain store
    float bbv[NTW];
#pragma unroll
    for (int nt = 0; nt < NTW; ++nt) bbv[nt] = bb[w * CW + nt * 16 + lr];

    const int myd = s_dst[l];
    const int pd  = s_dst[l == 0 ? 0 : l - 1];
    unsigned long long m = __ballot((l == 0) || (myd != pd));

    while (m) {
        const int a = __builtin_ctzll(m);
        const unsigned long long m2 = m & (m - 1);
        const int b = m2 ? __builtin_ctzll(m2) : 64;
        m = m2;
        const int d = s_dst[a];
        const bool interior = (a > 0) && (b < 64);
#pragma unroll
        for (int nt = 0; nt < NTW; ++nt) {
            float v = -INFINITY;
#pragma unroll
            for (int mm = 0; mm < 4; ++mm) {
                if (b <= mm * 16 || a >= mm * 16 + 16) continue;  // wave-uniform skip
#pragma unroll
                for (int rr = 0; rr < 4; ++rr) {
                    const int row = mm * 16 + lg * 4 + rr;
                    const bool in = (row >= a) && (row < b);
                    v = fmaxf(v, in ? acc[mm][nt][rr] : -INFINITY);
                }
            }
            v = fmaxf(v, __shfl_xor(v, 16, 64));
            v = fmaxf(v, __shfl_xor(v, 32, 64));
            if (lg == 0) {
                float* addr = &agg[(size_t)d * C + w * CW + nt * 16 + lr];
                if (interior) *addr = v + bbv[nt];
                else          atomic_max_f(addr, v + bbv[nt]);
            }
        }
    }
}

// ---------- projection step 1: coalesced atomic scatter into pixel-major img -
__global__ __launch_bounds__(256) void scatter_img(const float* __restrict__ feat, // N x 256
                                                   const float* __restrict__ pos,
                                                   const float* __restrict__ Km,
                                                   const int* __restrict__ batch,
                                                   float* __restrict__ img) {  // [B*4800][256]
    const int n0 = blockIdx.x * 8;
    const int c = threadIdx.x;
    const float k00 = Km[0], k02 = Km[2], k11 = Km[4], k12 = Km[5];
#pragma unroll
    for (int k = 0; k < 8; ++k) {
        const int n = n0 + k;
        const float X = pos[3 * n + 0], Y = pos[3 * n + 1], Z = pos[3 * n + 2];
        const int u = (int)((k00 * X / Z + k02) / 640.0f * 80.0f);
        const int v = (int)((k11 * Y / Z + k12) / 480.0f * 60.0f);
        if (u < 0 || u >= 80 || v < 0 || v >= 60) continue;
        const int p = (batch[n] * 60 + v) * 80 + u;
        float val = feat[(size_t)n * 256 + c];
        if (!isfinite(val)) val = 0.0f;
        atomicAdd(img + (size_t)p * 256 + c, val);
    }
}

// ---------- projection step 2: tiled transpose img[b][p][c] -> out[b][c][p] --
__global__ __launch_bounds__(256) void transpose_img(const float* __restrict__ img,
                                                     float* __restrict__ out) {
    __shared__ float tile[32][33];
    const int b = blockIdx.z;
    const int p0 = blockIdx.x * 32, c0 = blockIdx.y * 32;
    const float* src = img + (size_t)b * 4800 * 256;
    float* dst = out + (size_t)b * 256 * 4800;
    const int tx = threadIdx.x & 31, ty = threadIdx.x >> 5;
#pragma unroll
    for (int i = 0; i < 32; i += 8)
        tile[ty + i][tx] = src[(size_t)(p0 + ty + i) * 256 + c0 + tx];
    __syncthreads();
#pragma unroll
    for (int i = 0; i < 32; i += 8)
        dst[(size_t)(c0 + ty + i) * 4800 + p0 + tx] = tile[tx][ty + i];
}

// ---------------------------------------------------------------------------
extern "C" void kernel_launch(void* const* d_in, const int* in_sizes, int n_in,
                              void* d_out, int out_size, void* d_ws, size_t ws_size,
                              hipStream_t stream) {
    const float* x   = (const float*)d_in[0];
    const float* pos = (const float*)d_in[1];
    const float* Km  = (const float*)d_in[2];
    const float* w11 = (const float*)d_in[3];
    const float* b11 = (const float*)d_in[4];
    const float* w12 = (const float*)d_in[5];
    const float* b12 = (const float*)d_in[6];
    const float* w21 = (const float*)d_in[7];
    const float* b21 = (const float*)d_in[8];
    const float* w22 = (const float*)d_in[9];
    const float* b22 = (const float*)d_in[10];
    const float* w31 = (const float*)d_in[11];
    const float* b31 = (const float*)d_in[12];
    const float* w32 = (const float*)d_in[13];
    const float* b32 = (const float*)d_in[14];
    const int* edge  = (const int*)d_in[15];
    const int* batch = (const int*)d_in[16];
    const int* srcp = edge;
    const int* dstp = edge + NE;
    float* out = (float*)d_out;

    // workspace layout
    float* aggA  = (float*)d_ws;                      // N x 256 f32 (also img buffer)
    float* aggB  = aggA + (size_t)NN * 256;           // N x 256 f32
    f16*   Ah    = (f16*)(aggB + (size_t)NN * 256);   // N x 256 f16
    int*   srcS  = (int*)(Ah + (size_t)NN * 256);     // E
    int*   dstS  = srcS + NE;                         // E
    int*   counts = dstS + NE;                        // N
    int*   cursor = counts + NN;                      // N
    f16*   pW1   = (f16*)(cursor + NN);               // 64*64
    f16*   pW2   = pW1 + 64 * 64;                     // 128*128
    f16*   pW3   = pW2 + 128 * 128;                   // 256*256
    f16*   pW2n  = pW3 + 256 * 256;                   // 64*128  (node L2)
    f16*   pW3n  = pW2n + 64 * 128;                   // 128*256 (node L3)
    f16*   wr1   = pW3n + 128 * 256;                  // 3*64 f16
    f16*   wr2   = wr1 + 3 * 64;                      // 3*128
    f16*   wr3   = wr2 + 3 * 128;                     // 3*256

    // ---- sort edges by dst (reused by all 3 layers)
    hipMemsetAsync(counts, 0, NN * sizeof(int), stream);
    hist_dst<<<(NE + 255) / 256, 256, 0, stream>>>(dstp, counts);
    scan_counts<<<1, 1024, 0, stream>>>(counts, cursor);
    scatter_edges<<<(NE + 255) / 256, 256, 0, stream>>>(srcp, dstp, cursor, srcS, dstS);

    // ---- fused prep: all weight packs + warel casts in one launch (128320 elems)
    prep_all<<<(128320 + 255) / 256, 256, 0, stream>>>(
        w12, pW1, w22, pW2, w32, pW3, w21, pW2n, w31, pW3n,
        w11 + 16 * 64, wr1, w21 + 64 * 128, wr2, w31 + 128 * 256, wr3);

    // ---- layer 1: cin=16, cout=64
    node_linear<16, 64><<<NN / 8, 256, 0, stream>>>(x, w11, b11, Ah);
    fill_neg_inf4<<<512, 256, 0, stream>>>((float4*)aggB, NN * 64 / 4);
    edge_mfma<64, 4><<<NE / 64, 256, 0, stream>>>(Ah, wr1, pW1, b12,
                                                  pos, srcS, dstS, aggB);
    // ---- layer 2: cin=64, cout=128
    node_gemm<64, 128><<<(NN + 63) / 64, 256, 0, stream>>>(aggB, pW2n, b21, Ah);
    fill_neg_inf4<<<512, 256, 0, stream>>>((float4*)aggA, NN * 128 / 4);
    edge_mfma<128, 8><<<NE / 64, 512, 0, stream>>>(Ah, wr2, pW2, b22,
                                                   pos, srcS, dstS, aggA);
    // ---- layer 3: cin=128, cout=256
    node_gemm<128, 256><<<(NN + 63) / 64, 256, 0, stream>>>(aggA, pW3n, b31, Ah);
    fill_neg_inf4<<<512, 256, 0, stream>>>((float4*)aggB, NN * 256 / 4);
    edge_mfma<256, 8><<<NE / 64, 512, 0, stream>>>(Ah, wr3, pW3, b32,
                                                   pos, srcS, dstS, aggB);
    // ---- projection: coalesced scatter into pixel-major img, then transpose
    hipMemsetAsync(aggA, 0, (size_t)4 * 4800 * 256 * sizeof(float), stream);
    scatter_img<<<NN / 8, 256, 0, stream>>>(aggB, pos, Km, batch, aggA);
    transpose_img<<<dim3(150, 8, 4), 256, 0, stream>>>(aggA, out);
}

// Round 13
// 367.602 us; speedup vs baseline: 1.4119x; 1.0017x over previous
//
#include <hip/hip_runtime.h>
#include <math.h>

#define NN 30000
#define NE 400000

typedef _Float16 f16;
typedef _Float16 f16x8 __attribute__((ext_vector_type(8)));
typedef _Float16 f16x4 __attribute__((ext_vector_type(4)));
typedef float f32x4 __attribute__((ext_vector_type(4)));

// ---------- float atomic max via int/uint atomics (valid incl. -inf init) ----
__device__ __forceinline__ void atomic_max_f(float* addr, float v) {
    if (v >= 0.0f) {
        atomicMax((int*)addr, __float_as_int(v));
    } else {
        atomicMin((unsigned int*)addr, __float_as_uint(v));
    }
}

__global__ __launch_bounds__(256) void fill_neg_inf4(float4* p, int n4) {
    int i = blockIdx.x * blockDim.x + threadIdx.x;
    int stride = gridDim.x * blockDim.x;
    const float4 v = {-INFINITY, -INFINITY, -INFINITY, -INFINITY};
    for (; i < n4; i += stride) p[i] = v;
}

// ---------- counting-sort of edges by dst --------------------------------
__global__ __launch_bounds__(256) void hist_dst(const int* __restrict__ dst,
                                                int* __restrict__ counts) {
    int e = blockIdx.x * 256 + threadIdx.x;
    if (e < NE) atomicAdd(&counts[dst[e]], 1);
}

__global__ __launch_bounds__(1024) void scan_counts(const int* __restrict__ counts,
                                                    int* __restrict__ cursor) {
    __shared__ int lsum[1024];
    const int t = threadIdx.x;
    const int base = t * 30;
    int s = 0;
    for (int i = 0; i < 30; ++i) {
        int idx = base + i;
        if (idx < NN) s += counts[idx];
    }
    lsum[t] = s;
    __syncthreads();
    int acc = s;
    for (int off = 1; off < 1024; off <<= 1) {
        int v = (t >= off) ? lsum[t - off] : 0;
        __syncthreads();
        acc += v;
        lsum[t] = acc;
        __syncthreads();
    }
    int run = acc - s;
    for (int i = 0; i < 30; ++i) {
        int idx = base + i;
        if (idx < NN) { cursor[idx] = run; run += counts[idx]; }
    }
}

__global__ __launch_bounds__(256) void scatter_edges(const int* __restrict__ src,
                                                     const int* __restrict__ dst,
                                                     int* __restrict__ cursor,
                                                     int* __restrict__ srcS,
                                                     int* __restrict__ dstS) {
    int e = blockIdx.x * 256 + threadIdx.x;
    if (e >= NE) return;
    int d = dst[e];
    int p = atomicAdd(&cursor[d], 1);
    srcS[p] = src[e];
    dstS[p] = d;
}

// ---------- fused prep: 5 packs + 3 casts + 2 hoisted agg fills, ONE launch --
__device__ __forceinline__ void pack_one(const float* __restrict__ wsrc,
                                         f16* __restrict__ pB, int f, int K, int N) {
    int j = f & 7;
    int l = (f >> 3) & 63;
    int rest = f >> 9;
    int KS = K >> 5;
    int ks = rest % KS;
    int nt = rest / KS;
    int k = ks * 32 + ((l >> 4) << 3) + j;
    int n = nt * 16 + (l & 15);
    pB[f] = (f16)wsrc[k * N + n];
}

__global__ __launch_bounds__(256) void prep_all(const float* __restrict__ w12, f16* pW1,
                                                const float* __restrict__ w22, f16* pW2,
                                                const float* __restrict__ w32, f16* pW3,
                                                const float* __restrict__ w21, f16* pW2n,
                                                const float* __restrict__ w31, f16* pW3n,
                                                const float* __restrict__ wr1s, f16* wr1,
                                                const float* __restrict__ wr2s, f16* wr2,
                                                const float* __restrict__ wr3s, f16* wr3,
                                                float4* fillB, int nB4,
                                                float4* fillA, int nA4) {
    int i = blockIdx.x * 256 + threadIdx.x;
    const int stride = gridDim.x * 256;
    {   // packs + casts: ranges 4096 | 16384 | 65536 | 8192 | 32768 | 192 | 384 | 768
        int k = i;
        if (k < 4096) { pack_one(w12, pW1, k, 64, 64); }
        else if ((k -= 4096) < 16384) { pack_one(w22, pW2, k, 128, 128); }
        else if ((k -= 16384) < 65536) { pack_one(w32, pW3, k, 256, 256); }
        else if ((k -= 65536) < 8192) { pack_one(w21, pW2n, k, 64, 128); }
        else if ((k -= 8192) < 32768) { pack_one(w31, pW3n, k, 128, 256); }
        else if ((k -= 32768) < 192) { wr1[k] = (f16)wr1s[k]; }
        else if ((k -= 192) < 384) { wr2[k] = (f16)wr2s[k]; }
        else if ((k -= 384) < 768) { wr3[k] = (f16)wr3s[k]; }
    }
    const float4 NEG = {-INFINITY, -INFINITY, -INFINITY, -INFINITY};
    for (int k = i; k < nB4; k += stride) fillB[k] = NEG;
    for (int k = i; k < nA4; k += stride) fillA[k] = NEG;
}

// ---------- layer-1 node linear (K=16, tiny): scalar -------------------------
template<int K, int COUT>
__global__ __launch_bounds__(256) void node_linear(const float* __restrict__ feat,
                                                   const float* __restrict__ wa,
                                                   const float* __restrict__ b,
                                                   f16* __restrict__ A) {
    constexpr int NPB = 8;
    constexpr int G   = 256 / COUT;
    constexpr int NPT = NPB / G;
    __shared__ float sf[NPB * K];
    const int node0 = blockIdx.x * NPB;
    for (int idx = threadIdx.x; idx < NPB * K; idx += 256) {
        float v = feat[node0 * K + idx];
        if (!isfinite(v)) v = 0.0f;
        sf[idx] = v;
    }
    __syncthreads();
    const int j  = threadIdx.x % COUT;
    const int g  = threadIdx.x / COUT;
    const int n0 = g * NPT;
    float acc[NPT];
#pragma unroll
    for (int i = 0; i < NPT; i++) acc[i] = 0.0f;
    for (int k = 0; k < K; k++) {
        float w = wa[k * COUT + j];
#pragma unroll
        for (int nn = 0; nn < NPT; nn++)
            acc[nn] = fmaf(sf[(n0 + nn) * K + k], w, acc[nn]);
    }
    const float bj = b[j];
#pragma unroll
    for (int nn = 0; nn < NPT; nn++)
        A[(size_t)(node0 + n0 + nn) * COUT + j] = (f16)(acc[nn] + bj);
}

// ---------- node GEMM via MFMA: A[n][C] = fixup(feat[n][K]) @ wa + bias -> f16
template<int K, int C>
__global__ __launch_bounds__(256) void node_gemm(const float* __restrict__ feat,
                                                 const f16* __restrict__ pW,
                                                 const float* __restrict__ bias,
                                                 f16* __restrict__ A) {
    constexpr int NTW = C / 64;
    constexpr int KS  = K / 32;
    __shared__ __align__(16) unsigned char smem[64 * K * 2];
    const int tid = threadIdx.x;
    const int node0 = blockIdx.x * 64;

    {
        const int e = tid >> 2, p = tid & 3;
        const bool valid = (node0 + e) < NN;
        const float* frow = feat + (size_t)(node0 + e) * K;
#pragma unroll
        for (int ch = 0; ch < K / 32; ++ch) {
            const int j0 = (ch * 4 + p) * 8;
            f16x8 hv;
#pragma unroll
            for (int jj = 0; jj < 8; ++jj) {
                float v = valid ? frow[j0 + jj] : 0.0f;
                if (!isfinite(v)) v = 0.0f;
                hv[jj] = (f16)v;
            }
            *(f16x8*)(smem + e * (K * 2) + ((j0 * 2) ^ ((e & 7) << 4))) = hv;
        }
    }
    __syncthreads();

    const int w = tid >> 6, l = tid & 63, lr = l & 15, lg = l >> 4;
    f32x4 acc[4][NTW] = {};
#pragma unroll
    for (int ks = 0; ks < KS; ++ks) {
        f16x8 af[4];
#pragma unroll
        for (int m = 0; m < 4; ++m) {
            const int row = m * 16 + lr;
            af[m] = *(const f16x8*)(smem + row * (K * 2)
                     + (((ks * 32 + lg * 8) * 2) ^ ((row & 7) << 4)));
        }
#pragma unroll
        for (int nt = 0; nt < NTW; ++nt) {
            const int ntg = w * NTW + nt;
            f16x8 bf = *(const f16x8*)(pW + ((size_t)(ntg * KS + ks) * 64 + l) * 8);
#pragma unroll
            for (int m = 0; m < 4; ++m)
                acc[m][nt] = __builtin_amdgcn_mfma_f32_16x16x32_f16(af[m], bf, acc[m][nt], 0, 0, 0);
        }
    }
#pragma unroll
    for (int m = 0; m < 4; ++m)
#pragma unroll
        for (int nt = 0; nt < NTW; ++nt) {
            const int col = w * (C / 4) + nt * 16 + lr;
            const float bv = bias[col];
#pragma unroll
            for (int rr = 0; rr < 4; ++rr) {
                const int row = m * 16 + lg * 4 + rr;
                if (node0 + row < NN)
                    A[(size_t)(node0 + row) * C + col] = (f16)(acc[m][nt][rr] + bv);
            }
        }
}

// ---------- edge kernel (TE=64): early-issue A-gather; h1 in LDS; MFMA;
//            ballot segmented max; interior runs -> plain store ---------------
template<int C, int NW>
__global__ __launch_bounds__(NW * 64, 4) void edge_mfma(const f16* __restrict__ Ah,
                                                        const f16* __restrict__ warelh, // 3 x C f16
                                                        const f16* __restrict__ pB,
                                                        const float* __restrict__ bb,
                                                        const float* __restrict__ pos,
                                                        const int* __restrict__ srcS,
                                                        const int* __restrict__ dstS,
                                                        float* __restrict__ agg) {
    constexpr int TE   = 64;
    constexpr int BLK  = NW * 64;
    constexpr int CW   = C / NW;        // cols per wave
    constexpr int NTW  = CW / 16;       // n-tiles per wave
    constexpr int KS   = C / 32;        // k-steps
    constexpr int CPR  = C / 8;         // f16x8 chunks per row
    constexpr int LOGCPR = (C == 256) ? 5 : (C == 128 ? 4 : 3);
    constexpr int CH   = (TE * CPR) / BLK;  // chunks per thread
    static_assert(NTW >= 1 && CH >= 2, "geometry");

    __shared__ __align__(16) unsigned char h1[TE * C * 2];  // f16, XOR-swizzled
    __shared__ __align__(16) f16 s_warel[3 * C];
    __shared__ __align__(8)  f16 s_rel[TE][4];
    __shared__ int s_dst[TE];

    const int tid = threadIdx.x;
    const int nwg = gridDim.x;
    const int q8 = nwg >> 3, r8 = nwg & 7;
    const int xcd = blockIdx.x & 7, o = blockIdx.x >> 3;
    const int bid = (xcd < r8 ? xcd * (q8 + 1) : r8 * (q8 + 1) + (xcd - r8) * q8) + o;
    const int e0 = bid * TE;

    // ---- early-issue A-gather (no dependence on the meta barrier)
    const int slot = tid & (CPR - 1);
    int sv[CH];
    f16x8 av[CH];
#pragma unroll
    for (int i = 0; i < CH; ++i)
        sv[i] = srcS[e0 + ((i * BLK + tid) >> LOGCPR)];
    av[0] = *(const f16x8*)(Ah + (size_t)sv[0] * C + slot * 8);
    av[1] = *(const f16x8*)(Ah + (size_t)sv[1] * C + slot * 8);

    // ---- meta: rel (f16) + dst into LDS
    if (tid < TE) {
        int s = srcS[e0 + tid], d = dstS[e0 + tid];
        s_dst[tid] = d;
        s_rel[tid][0] = (f16)(pos[3 * s + 0] - pos[3 * d + 0]);
        s_rel[tid][1] = (f16)(pos[3 * s + 1] - pos[3 * d + 1]);
        s_rel[tid][2] = (f16)(pos[3 * s + 2] - pos[3 * d + 2]);
        s_rel[tid][3] = (f16)0.f;
    }
    for (int i = tid; i < 3 * C / 8; i += BLK)
        ((f16x8*)s_warel)[i] = ((const f16x8*)warelh)[i];
    __syncthreads();

    // ---- phase 1: h1 = relu(A[src] + rel@warel) into LDS (packed f16)
    {
        const f16* wp = s_warel + slot * 8;
        const f16x8 w0 = *(const f16x8*)(wp);
        const f16x8 w1 = *(const f16x8*)(wp + C);
        const f16x8 w2 = *(const f16x8*)(wp + 2 * C);
#pragma unroll
        for (int i = 0; i < CH; ++i) {
            if (i + 2 < CH)  // keep 2 gathers in flight
                av[i + 2] = *(const f16x8*)(Ah + (size_t)sv[i + 2] * C + slot * 8);
            const int row = (i * BLK + tid) >> LOGCPR;
            const f16x4 rl = *(const f16x4*)&s_rel[row][0];
            const f16 rx = rl[0], ry = rl[1], rz = rl[2];
            const f16x8 rxv = {rx, rx, rx, rx, rx, rx, rx, rx};
            const f16x8 ryv = {ry, ry, ry, ry, ry, ry, ry, ry};
            const f16x8 rzv = {rz, rz, rz, rz, rz, rz, rz, rz};
            f16x8 hv = av[i] + rxv * w0 + ryv * w1 + rzv * w2;
#pragma unroll
            for (int jj = 0; jj < 8; ++jj)
                hv[jj] = hv[jj] > (f16)0.f ? hv[jj] : (f16)0.f;
            *(f16x8*)(h1 + row * (2 * C) + ((slot * 16) ^ ((row & 7) << 4))) = hv;
        }
    }
    __syncthreads();

    // ---- phase 2: msg = h1 @ wb via MFMA (wave: 64 rows x CW cols)
    const int w = tid >> 6, l = tid & 63, lr = l & 15, lg = l >> 4;
    f32x4 acc[4][NTW] = {};
    __builtin_amdgcn_s_setprio(1);
#pragma unroll
    for (int ks = 0; ks < KS; ++ks) {
        f16x8 af[4];
#pragma unroll
        for (int m = 0; m < 4; ++m) {
            const int row = m * 16 + lr;
            af[m] = *(const f16x8*)(h1 + row * (2 * C)
                     + (((ks * 32 + lg * 8) * 2) ^ ((row & 7) << 4)));
        }
#pragma unroll
        for (int nt = 0; nt < NTW; ++nt) {
            f16x8 bf = *(const f16x8*)(pB + ((size_t)((w * NTW + nt) * KS + ks) * 64 + l) * 8);
#pragma unroll
            for (int m = 0; m < 4; ++m)
                acc[m][nt] = __builtin_amdgcn_mfma_f32_16x16x32_f16(af[m], bf, acc[m][nt], 0, 0, 0);
        }
    }
    __builtin_amdgcn_s_setprio(0);

    // ---- phase 3: register segmented max; interior run -> plain store
    float bbv[NTW];
#pragma unroll
    for (int nt = 0; nt < NTW; ++nt) bbv[nt] = bb[w * CW + nt * 16 + lr];

    const int myd = s_dst[l];
    const int pd  = s_dst[l == 0 ? 0 : l - 1];
    unsigned long long m = __ballot((l == 0) || (myd != pd));

    while (m) {
        const int a = __builtin_ctzll(m);
        const unsigned long long m2 = m & (m - 1);
        const int b = m2 ? __builtin_ctzll(m2) : 64;
        m = m2;
        const int d = s_dst[a];
        const bool interior = (a > 0) && (b < 64);
#pragma unroll
        for (int nt = 0; nt < NTW; ++nt) {
            float v = -INFINITY;
#pragma unroll
            for (int mm = 0; mm < 4; ++mm) {
                if (b <= mm * 16 || a >= mm * 16 + 16) continue;  // wave-uniform skip
#pragma unroll
                for (int rr = 0; rr < 4; ++rr) {
                    const int row = mm * 16 + lg * 4 + rr;
                    const bool in = (row >= a) && (row < b);
                    v = fmaxf(v, in ? acc[mm][nt][rr] : -INFINITY);
                }
            }
            v = fmaxf(v, __shfl_xor(v, 16, 64));
            v = fmaxf(v, __shfl_xor(v, 32, 64));
            if (lg == 0) {
                float* addr = &agg[(size_t)d * C + w * CW + nt * 16 + lr];
                if (interior) *addr = v + bbv[nt];
                else          atomic_max_f(addr, v + bbv[nt]);
            }
        }
    }
}

// ---------- projection step 1: coalesced atomic scatter into pixel-major img -
__global__ __launch_bounds__(256) void scatter_img(const float* __restrict__ feat, // N x 256
                                                   const float* __restrict__ pos,
                                                   const float* __restrict__ Km,
                                                   const int* __restrict__ batch,
                                                   float* __restrict__ img) {  // [B*4800][256]
    const int n0 = blockIdx.x * 8;
    const int c = threadIdx.x;
    const float k00 = Km[0], k02 = Km[2], k11 = Km[4], k12 = Km[5];
#pragma unroll
    for (int k = 0; k < 8; ++k) {
        const int n = n0 + k;
        const float X = pos[3 * n + 0], Y = pos[3 * n + 1], Z = pos[3 * n + 2];
        const int u = (int)((k00 * X / Z + k02) / 640.0f * 80.0f);
        const int v = (int)((k11 * Y / Z + k12) / 480.0f * 60.0f);
        if (u < 0 || u >= 80 || v < 0 || v >= 60) continue;
        const int p = (batch[n] * 60 + v) * 80 + u;
        float val = feat[(size_t)n * 256 + c];
        if (!isfinite(val)) val = 0.0f;
        atomicAdd(img + (size_t)p * 256 + c, val);
    }
}

// ---------- projection step 2: tiled transpose img[b][p][c] -> out[b][c][p] --
__global__ __launch_bounds__(256) void transpose_img(const float* __restrict__ img,
                                                     float* __restrict__ out) {
    __shared__ float tile[32][33];
    const int b = blockIdx.z;
    const int p0 = blockIdx.x * 32, c0 = blockIdx.y * 32;
    const float* src = img + (size_t)b * 4800 * 256;
    float* dst = out + (size_t)b * 256 * 4800;
    const int tx = threadIdx.x & 31, ty = threadIdx.x >> 5;
#pragma unroll
    for (int i = 0; i < 32; i += 8)
        tile[ty + i][tx] = src[(size_t)(p0 + ty + i) * 256 + c0 + tx];
    __syncthreads();
#pragma unroll
    for (int i = 0; i < 32; i += 8)
        dst[(size_t)(c0 + ty + i) * 4800 + p0 + tx] = tile[tx][ty + i];
}

// ---------------------------------------------------------------------------
extern "C" void kernel_launch(void* const* d_in, const int* in_sizes, int n_in,
                              void* d_out, int out_size, void* d_ws, size_t ws_size,
                              hipStream_t stream) {
    const float* x   = (const float*)d_in[0];
    const float* pos = (const float*)d_in[1];
    const float* Km  = (const float*)d_in[2];
    const float* w11 = (const float*)d_in[3];
    const float* b11 = (const float*)d_in[4];
    const float* w12 = (const float*)d_in[5];
    const float* b12 = (const float*)d_in[6];
    const float* w21 = (const float*)d_in[7];
    const float* b21 = (const float*)d_in[8];
    const float* w22 = (const float*)d_in[9];
    const float* b22 = (const float*)d_in[10];
    const float* w31 = (const float*)d_in[11];
    const float* b31 = (const float*)d_in[12];
    const float* w32 = (const float*)d_in[13];
    const float* b32 = (const float*)d_in[14];
    const int* edge  = (const int*)d_in[15];
    const int* batch = (const int*)d_in[16];
    const int* srcp = edge;
    const int* dstp = edge + NE;
    float* out = (float*)d_out;

    // workspace layout
    float* aggA  = (float*)d_ws;                      // N x 256 f32 (also img buffer)
    float* aggB  = aggA + (size_t)NN * 256;           // N x 256 f32
    f16*   Ah    = (f16*)(aggB + (size_t)NN * 256);   // N x 256 f16
    int*   srcS  = (int*)(Ah + (size_t)NN * 256);     // E
    int*   dstS  = srcS + NE;                         // E
    int*   counts = dstS + NE;                        // N
    int*   cursor = counts + NN;                      // N
    f16*   pW1   = (f16*)(cursor + NN);               // 64*64
    f16*   pW2   = pW1 + 64 * 64;                     // 128*128
    f16*   pW3   = pW2 + 128 * 128;                   // 256*256
    f16*   pW2n  = pW3 + 256 * 256;                   // 64*128  (node L2)
    f16*   pW3n  = pW2n + 64 * 128;                   // 128*256 (node L3)
    f16*   wr1   = pW3n + 128 * 256;                  // 3*64 f16
    f16*   wr2   = wr1 + 3 * 64;                      // 3*128
    f16*   wr3   = wr2 + 3 * 128;                     // 3*256

    // ---- sort edges by dst (reused by all 3 layers)
    hipMemsetAsync(counts, 0, NN * sizeof(int), stream);
    hist_dst<<<(NE + 255) / 256, 256, 0, stream>>>(dstp, counts);
    scan_counts<<<1, 1024, 0, stream>>>(counts, cursor);
    scatter_edges<<<(NE + 255) / 256, 256, 0, stream>>>(srcp, dstp, cursor, srcS, dstS);

    // ---- fused prep: packs + casts + hoisted -inf fills (aggB L1, aggA L2)
    prep_all<<<1024, 256, 0, stream>>>(
        w12, pW1, w22, pW2, w32, pW3, w21, pW2n, w31, pW3n,
        w11 + 16 * 64, wr1, w21 + 64 * 128, wr2, w31 + 128 * 256, wr3,
        (float4*)aggB, NN * 64 / 4, (float4*)aggA, NN * 128 / 4);

    // ---- layer 1: cin=16, cout=64
    node_linear<16, 64><<<NN / 8, 256, 0, stream>>>(x, w11, b11, Ah);
    edge_mfma<64, 4><<<NE / 64, 256, 0, stream>>>(Ah, wr1, pW1, b12,
                                                  pos, srcS, dstS, aggB);
    // ---- layer 2: cin=64, cout=128
    node_gemm<64, 128><<<(NN + 63) / 64, 256, 0, stream>>>(aggB, pW2n, b21, Ah);
    edge_mfma<128, 8><<<NE / 64, 512, 0, stream>>>(Ah, wr2, pW2, b22,
                                                   pos, srcS, dstS, aggA);
    // ---- layer 3: cin=128, cout=256
    node_gemm<128, 256><<<(NN + 63) / 64, 256, 0, stream>>>(aggA, pW3n, b31, Ah);
    fill_neg_inf4<<<512, 256, 0, stream>>>((float4*)aggB, NN * 256 / 4);
    edge_mfma<256, 8><<<NE / 64, 512, 0, stream>>>(Ah, wr3, pW3, b32,
                                                   pos, srcS, dstS, aggB);
    // ---- projection: coalesced scatter into pixel-major img, then transpose
    hipMemsetAsync(aggA, 0, (size_t)4 * 4800 * 256 * sizeof(float), stream);
    scatter_img<<<NN / 8, 256, 0, stream>>>(aggB, pos, Km, batch, aggA);
    transpose_img<<<dim3(150, 8, 4), 256, 0, stream>>>(aggA, out);
}